// Round 1
// baseline (71396.191 us; speedup 1.0000x reference)
//
#include <hip/hip_runtime.h>

// ---------------- problem dims ----------------
#define Hdim 1024
#define Bdim 128
#define Tdim 256
#define Fdim 64
#define Pdim 512
#define OUTLEN 48

// ---------------- tiling ----------------
#define KC 64          // k-chunk staged per iteration
#define PITCH 72       // LDS row pitch in ushort (64 + 8 pad; 144B row stride, 16B aligned)

typedef float  f32x4  __attribute__((ext_vector_type(4)));
typedef short  s16x8  __attribute__((ext_vector_type(8)));
typedef unsigned short u16x4 __attribute__((ext_vector_type(4)));

__device__ __forceinline__ unsigned short f2bf(float f) {
  unsigned int u = __float_as_uint(f);
  u += 0x7FFFu + ((u >> 16) & 1u);          // round-to-nearest-even
  return (unsigned short)(u >> 16);
}
__device__ __forceinline__ float bf2f(unsigned short s) {
  return __uint_as_float(((unsigned int)s) << 16);
}

// convert 4 fp32 -> bf16 hi/lo pairs, store to LDS
__device__ __forceinline__ void cvt_store(unsigned short* hi, unsigned short* lo,
                                          int off, f32x4 v) {
  u16x4 hv, lv;
#pragma unroll
  for (int e = 0; e < 4; ++e) {
    unsigned short h = f2bf(v[e]);
    hv[e] = h;
    lv[e] = f2bf(v[e] - bf2f(h));
  }
  *reinterpret_cast<u16x4*>(hi + off) = hv;
  *reinterpret_cast<u16x4*>(lo + off) = lv;
}

// =====================================================================
// Fused GRU layer step:  h_out = GRUCell(x, h_in)   (PyTorch gate order r,z,n)
// Grid: 64 blocks (16 output cols each), 256 threads (4 waves x 32 batch rows).
// Accumulators: S_r = x.Wih_r + h.Whh_r ; S_z likewise ; A_in = x.Wih_n ; A_hn = h.Whh_n
// 3-term bf16 hi/lo split per MFMA for ~fp32 precision.
// =====================================================================
__global__ __launch_bounds__(256)
void gru_step_kernel(const float* __restrict__ x, int x_stride, int KX,
                     const float* __restrict__ h_in,
                     const float* __restrict__ Wih, const float* __restrict__ Whh,
                     const float* __restrict__ bih, const float* __restrict__ bhh,
                     float* __restrict__ h_out)
{
  __shared__ __align__(16) unsigned short a_hi[Bdim * PITCH];
  __shared__ __align__(16) unsigned short a_lo[Bdim * PITCH];
  __shared__ __align__(16) unsigned short w_hi[48 * PITCH];
  __shared__ __align__(16) unsigned short w_lo[48 * PITCH];

  const int tid  = threadIdx.x;
  const int lane = tid & 63;
  const int wv   = tid >> 6;
  const int colbase = blockIdx.x * 16;

  f32x4 accR[2], accZ[2], accIN[2], accHN[2];
#pragma unroll
  for (int i = 0; i < 2; ++i) {
    accR[i]  = f32x4{0.f, 0.f, 0.f, 0.f};
    accZ[i]  = f32x4{0.f, 0.f, 0.f, 0.f};
    accIN[i] = f32x4{0.f, 0.f, 0.f, 0.f};
    accHN[i] = f32x4{0.f, 0.f, 0.f, 0.f};
  }

#pragma unroll
  for (int phase = 0; phase < 2; ++phase) {
    const float* Ap  = phase ? h_in : x;
    const int    astr = phase ? Hdim : x_stride;
    const int    K    = phase ? Hdim : KX;
    const float* Wp  = phase ? Whh : Wih;

    for (int k0 = 0; k0 < K; k0 += KC) {
      __syncthreads();
      // ---- stage A tile [128 x 64] fp32 -> hi/lo bf16 ----
#pragma unroll
      for (int it = 0; it < 8; ++it) {
        int idx = tid + it * 256;          // 2048 float4 total
        int row = idx >> 4, kq = idx & 15;
        f32x4 v = *reinterpret_cast<const f32x4*>(Ap + (size_t)row * astr + k0 + kq * 4);
        cvt_store(a_hi, a_lo, row * PITCH + kq * 4, v);
      }
      // ---- stage W tile: 48 rows (3 gates x 16 cols) x 64 k ----
#pragma unroll
      for (int it = 0; it < 3; ++it) {
        int idx = tid + it * 256;          // 768 float4 total
        int wrow = idx >> 4, kq = idx & 15;
        int grow = (wrow >> 4) * Hdim + colbase + (wrow & 15);
        f32x4 v = *reinterpret_cast<const f32x4*>(Wp + (size_t)grow * K + k0 + kq * 4);
        cvt_store(w_hi, w_lo, wrow * PITCH + kq * 4, v);
      }
      __syncthreads();

#pragma unroll
      for (int kk = 0; kk < 2; ++kk) {
        const int koff = kk * 32 + (lane >> 4) * 8;
        s16x8 bh[3], bl[3];
#pragma unroll
        for (int g = 0; g < 3; ++g) {
          bh[g] = *reinterpret_cast<const s16x8*>(&w_hi[(g * 16 + (lane & 15)) * PITCH + koff]);
          bl[g] = *reinterpret_cast<const s16x8*>(&w_lo[(g * 16 + (lane & 15)) * PITCH + koff]);
        }
#pragma unroll
        for (int mf = 0; mf < 2; ++mf) {
          const int arow = wv * 32 + mf * 16 + (lane & 15);
          s16x8 ah = *reinterpret_cast<const s16x8*>(&a_hi[arow * PITCH + koff]);
          s16x8 al = *reinterpret_cast<const s16x8*>(&a_lo[arow * PITCH + koff]);

          accR[mf] = __builtin_amdgcn_mfma_f32_16x16x32_bf16(ah, bh[0], accR[mf], 0, 0, 0);
          accR[mf] = __builtin_amdgcn_mfma_f32_16x16x32_bf16(al, bh[0], accR[mf], 0, 0, 0);
          accR[mf] = __builtin_amdgcn_mfma_f32_16x16x32_bf16(ah, bl[0], accR[mf], 0, 0, 0);

          accZ[mf] = __builtin_amdgcn_mfma_f32_16x16x32_bf16(ah, bh[1], accZ[mf], 0, 0, 0);
          accZ[mf] = __builtin_amdgcn_mfma_f32_16x16x32_bf16(al, bh[1], accZ[mf], 0, 0, 0);
          accZ[mf] = __builtin_amdgcn_mfma_f32_16x16x32_bf16(ah, bl[1], accZ[mf], 0, 0, 0);

          if (phase == 0) {
            accIN[mf] = __builtin_amdgcn_mfma_f32_16x16x32_bf16(ah, bh[2], accIN[mf], 0, 0, 0);
            accIN[mf] = __builtin_amdgcn_mfma_f32_16x16x32_bf16(al, bh[2], accIN[mf], 0, 0, 0);
            accIN[mf] = __builtin_amdgcn_mfma_f32_16x16x32_bf16(ah, bl[2], accIN[mf], 0, 0, 0);
          } else {
            accHN[mf] = __builtin_amdgcn_mfma_f32_16x16x32_bf16(ah, bh[2], accHN[mf], 0, 0, 0);
            accHN[mf] = __builtin_amdgcn_mfma_f32_16x16x32_bf16(al, bh[2], accHN[mf], 0, 0, 0);
            accHN[mf] = __builtin_amdgcn_mfma_f32_16x16x32_bf16(ah, bl[2], accHN[mf], 0, 0, 0);
          }
        }
      }
    }
  }

  // ---- epilogue: gate math, write h_out ----
  const int j = colbase + (lane & 15);
  const float b_r  = bih[j]          + bhh[j];
  const float b_z  = bih[Hdim + j]   + bhh[Hdim + j];
  const float b_in = bih[2 * Hdim + j];
  const float b_hn = bhh[2 * Hdim + j];
#pragma unroll
  for (int mf = 0; mf < 2; ++mf) {
#pragma unroll
    for (int q = 0; q < 4; ++q) {
      int brow = wv * 32 + mf * 16 + (lane >> 4) * 4 + q;
      float r  = 1.f / (1.f + expf(-(accR[mf][q] + b_r)));
      float zg = 1.f / (1.f + expf(-(accZ[mf][q] + b_z)));
      float n  = tanhf(accIN[mf][q] + b_in + r * (accHN[mf][q] + b_hn));
      float hp = h_in[(size_t)brow * Hdim + j];
      h_out[(size_t)brow * Hdim + j] = (1.f - zg) * n + zg * hp;
    }
  }
}

// =====================================================================
// Linear: out = A @ W^T + bias, optional ReLU, optional second output copy.
// A [128 x K], W [N x K]; grid = N/16 blocks, 256 threads.
// =====================================================================
__global__ __launch_bounds__(256)
void linear_kernel(const float* __restrict__ A, int a_stride, int K,
                   const float* __restrict__ W, const float* __restrict__ bias,
                   float* __restrict__ out1, int out1_stride,
                   float* __restrict__ out2, int out2_stride, int relu)
{
  __shared__ __align__(16) unsigned short a_hi[Bdim * PITCH];
  __shared__ __align__(16) unsigned short a_lo[Bdim * PITCH];
  __shared__ __align__(16) unsigned short w_hi[16 * PITCH];
  __shared__ __align__(16) unsigned short w_lo[16 * PITCH];

  const int tid  = threadIdx.x;
  const int lane = tid & 63;
  const int wv   = tid >> 6;
  const int colbase = blockIdx.x * 16;

  f32x4 acc[2];
  acc[0] = f32x4{0.f, 0.f, 0.f, 0.f};
  acc[1] = f32x4{0.f, 0.f, 0.f, 0.f};

  for (int k0 = 0; k0 < K; k0 += KC) {
    __syncthreads();
#pragma unroll
    for (int it = 0; it < 8; ++it) {
      int idx = tid + it * 256;
      int row = idx >> 4, kq = idx & 15;
      f32x4 v = *reinterpret_cast<const f32x4*>(A + (size_t)row * a_stride + k0 + kq * 4);
      cvt_store(a_hi, a_lo, row * PITCH + kq * 4, v);
    }
    {
      int wrow = tid >> 4, kq = tid & 15;   // 256 float4 = 16 rows x 16
      int grow = colbase + wrow;
      f32x4 v = *reinterpret_cast<const f32x4*>(W + (size_t)grow * K + k0 + kq * 4);
      cvt_store(w_hi, w_lo, wrow * PITCH + kq * 4, v);
    }
    __syncthreads();

#pragma unroll
    for (int kk = 0; kk < 2; ++kk) {
      const int koff = kk * 32 + (lane >> 4) * 8;
      s16x8 bh = *reinterpret_cast<const s16x8*>(&w_hi[(lane & 15) * PITCH + koff]);
      s16x8 bl = *reinterpret_cast<const s16x8*>(&w_lo[(lane & 15) * PITCH + koff]);
#pragma unroll
      for (int mf = 0; mf < 2; ++mf) {
        const int arow = wv * 32 + mf * 16 + (lane & 15);
        s16x8 ah = *reinterpret_cast<const s16x8*>(&a_hi[arow * PITCH + koff]);
        s16x8 al = *reinterpret_cast<const s16x8*>(&a_lo[arow * PITCH + koff]);
        acc[mf] = __builtin_amdgcn_mfma_f32_16x16x32_bf16(ah, bh, acc[mf], 0, 0, 0);
        acc[mf] = __builtin_amdgcn_mfma_f32_16x16x32_bf16(al, bh, acc[mf], 0, 0, 0);
        acc[mf] = __builtin_amdgcn_mfma_f32_16x16x32_bf16(ah, bl, acc[mf], 0, 0, 0);
      }
    }
  }

  const int j = colbase + (lane & 15);
  const float bb = bias[j];
#pragma unroll
  for (int mf = 0; mf < 2; ++mf) {
#pragma unroll
    for (int q = 0; q < 4; ++q) {
      int brow = wv * 32 + mf * 16 + (lane >> 4) * 4 + q;
      float v = acc[mf][q] + bb;
      if (relu) v = fmaxf(v, 0.f);
      out1[(size_t)brow * out1_stride + j] = v;
      if (out2) out2[(size_t)brow * out2_stride + j] = v;
    }
  }
}

// =====================================================================
extern "C" void kernel_launch(void* const* d_in, const int* in_sizes, int n_in,
                              void* d_out, int out_size, void* d_ws, size_t ws_size,
                              hipStream_t stream) {
  const float* X      = (const float*)d_in[0];
  const float* eWih0  = (const float*)d_in[1];
  const float* eWhh0  = (const float*)d_in[2];
  const float* ebih0  = (const float*)d_in[3];
  const float* ebhh0  = (const float*)d_in[4];
  const float* eWih1  = (const float*)d_in[5];
  const float* eWhh1  = (const float*)d_in[6];
  const float* ebih1  = (const float*)d_in[7];
  const float* ebhh1  = (const float*)d_in[8];
  const float* dWih0  = (const float*)d_in[9];
  const float* dWhh0  = (const float*)d_in[10];
  const float* dbih0  = (const float*)d_in[11];
  const float* dbhh0  = (const float*)d_in[12];
  const float* dWih1  = (const float*)d_in[13];
  const float* dWhh1  = (const float*)d_in[14];
  const float* dbih1  = (const float*)d_in[15];
  const float* dbhh1  = (const float*)d_in[16];
  const float* projW  = (const float*)d_in[17];
  const float* projb  = (const float*)d_in[18];
  const float* outW   = (const float*)d_in[19];
  const float* outb   = (const float*)d_in[20];

  float* out = (float*)d_out;
  float* ws  = (float*)d_ws;

  const int HB = Bdim * Hdim;            // 131072
  float* h0buf = ws;                     // [2][128*1024]
  float* h1buf = ws + 2 * HB;            // [2][128*1024]
  float* pbuf  = ws + 4 * HB;            // [128*512]
  float* ybuf  = pbuf + Bdim * Pdim;     // [2][128*64]

  // zero initial hidden states (both ping-pong slots of h0 and h1)
  hipMemsetAsync(h0buf, 0, (size_t)4 * HB * sizeof(float), stream);

  // ---------------- encoder ----------------
  for (int t = 0; t < Tdim; ++t) {
    const float* xt = X + (size_t)t * Fdim;          // row stride T*F
    float* h0i = h0buf + (t & 1) * HB;
    float* h0o = h0buf + ((t + 1) & 1) * HB;
    float* h1i = h1buf + (t & 1) * HB;
    float* h1o = h1buf + ((t + 1) & 1) * HB;
    gru_step_kernel<<<64, 256, 0, stream>>>(xt, Tdim * Fdim, Fdim,
                                            h0i, eWih0, eWhh0, ebih0, ebhh0, h0o);
    gru_step_kernel<<<64, 256, 0, stream>>>(h0o, Hdim, Hdim,
                                            h1i, eWih1, eWhh1, ebih1, ebhh1, h1o);
  }

  // ---------------- decoder ----------------
  // encoder ended with latest h in slot 0; decoder step s: in = s&1, out = (s+1)&1
  for (int s = 0; s < OUTLEN; ++s) {
    const float* xs;
    int xstride;
    if (s == 0) { xs = X + (size_t)(Tdim - 1) * Fdim; xstride = Tdim * Fdim; }
    else        { xs = ybuf + ((s + 1) & 1) * (Bdim * Fdim); xstride = Fdim; }

    float* h0i = h0buf + (s & 1) * HB;
    float* h0o = h0buf + ((s + 1) & 1) * HB;
    float* h1i = h1buf + (s & 1) * HB;
    float* h1o = h1buf + ((s + 1) & 1) * HB;

    gru_step_kernel<<<64, 256, 0, stream>>>(xs, xstride, Fdim,
                                            h0i, dWih0, dWhh0, dbih0, dbhh0, h0o);
    gru_step_kernel<<<64, 256, 0, stream>>>(h0o, Hdim, Hdim,
                                            h1i, dWih1, dWhh1, dbih1, dbhh1, h1o);
    // p = relu(h1o @ projW^T + projb)
    linear_kernel<<<Pdim / 16, 256, 0, stream>>>(h1o, Hdim, Hdim, projW, projb,
                                                 pbuf, Pdim, nullptr, 0, 1);
    // y = p @ outW^T + outb  -> ybuf slot (next step input) + d_out[:, s, :]
    float* ycur = ybuf + (s & 1) * (Bdim * Fdim);
    linear_kernel<<<Fdim / 16, 256, 0, stream>>>(pbuf, Pdim, Pdim, outW, outb,
                                                 ycur, Fdim,
                                                 out + (size_t)s * Fdim, OUTLEN * Fdim, 0);
  }
}

// Round 3
// 30715.399 us; speedup vs baseline: 2.3244x; 2.3244x over previous
//
#include <hip/hip_runtime.h>

#define Bdim 128
#define Tdim 256
#define Fdim 64
#define Hdim 1024
#define Pdim 512
#define OUTLEN 48

typedef float  f32x4 __attribute__((ext_vector_type(4)));
typedef short  s16x8 __attribute__((ext_vector_type(8)));
typedef unsigned short u16;

__device__ __forceinline__ u16 f2bf(float f) {
  unsigned u = __float_as_uint(f);
  u += 0x7FFFu + ((u >> 16) & 1u);   // RNE
  return (u16)(u >> 16);
}
__device__ __forceinline__ float bf2f(u16 s) { return __uint_as_float(((unsigned)s) << 16); }
// 16B-block XOR swizzle within a 128B row (G4 pattern); returns ushort offset of block
__device__ __forceinline__ int swz8(int row, int blk) { return ((blk ^ (row & 7)) << 3); }

__device__ __forceinline__ f32x4 mfma16(s16x8 a, s16x8 b, f32x4 c) {
  return __builtin_amdgcn_mfma_f32_16x16x32_bf16(a, b, c, 0, 0, 0);
}

// async global->LDS, 16B per lane; lds base must be wave-uniform (HW adds lane*16)
__device__ __forceinline__ void glds16(u16* lds, const u16* g) {
  __builtin_amdgcn_global_load_lds(
      (const __attribute__((address_space(1))) unsigned int*)g,
      (__attribute__((address_space(3))) unsigned int*)lds, 16, 0, 0);
}

// =====================================================================
// prep: fp32 weight [N][K] -> swizzled bf16 hi/lo plane tiles
// layout: [colblk][nc][2(hi,lo)][rows][64]  (rows = 48 gru / 16 lin)
// =====================================================================
__global__ __launch_bounds__(256)
void prep_w(const float* __restrict__ W, u16* __restrict__ dst,
            int colblks, int nc, int rows, int K, int gru) {
  int idx = blockIdx.x * 256 + threadIdx.x;
  if (idx >= colblks * nc * rows * 8) return;
  int blk = idx & 7;
  int t = idx >> 3;
  int r = t % rows; t /= rows;
  int c = t % nc;
  int cb = t / nc;
  int srow = gru ? ((r >> 4) * Hdim + cb * 16 + (r & 15)) : (cb * 16 + r);
  const float* src = W + (size_t)srow * K + c * 64 + blk * 8;
  s16x8 vh, vl;
#pragma unroll
  for (int e = 0; e < 8; ++e) {
    float v = src[e];
    u16 h = f2bf(v);
    vh[e] = (short)h;
    vl[e] = (short)f2bf(v - bf2f(h));
  }
  size_t tb = (size_t)(cb * nc + c) * (2 * rows * 64);
  int o = r * 64 + swz8(r, blk);
  *(s16x8*)(dst + tb + o) = vh;
  *(s16x8*)(dst + tb + (size_t)rows * 64 + o) = vl;
}

// X [128][256][64] fp32 -> per-t A-tiles [256][2][128][64]
__global__ __launch_bounds__(256)
void prep_x(const float* __restrict__ X, u16* __restrict__ dst) {
  int idx = blockIdx.x * 256 + threadIdx.x;   // 256*128*8
  int blk = idx & 7;
  int row = (idx >> 3) & 127;
  int t = idx >> 10;
  const float* src = X + (size_t)row * (Tdim * Fdim) + t * 64 + blk * 8;
  s16x8 vh, vl;
#pragma unroll
  for (int e = 0; e < 8; ++e) {
    float v = src[e];
    u16 h = f2bf(v);
    vh[e] = (short)h;
    vl[e] = (short)f2bf(v - bf2f(h));
  }
  size_t tb = (size_t)t * 16384;
  int o = row * 64 + swz8(row, blk);
  *(s16x8*)(dst + tb + o) = vh;
  *(s16x8*)(dst + tb + 8192 + o) = vl;
}

// =====================================================================
// one staged 64-k chunk of MFMA work (3-term hi/lo split)
// =====================================================================
template<int NG, bool SEG1>
__device__ __forceinline__ void compute_chunk(const u16* __restrict__ A, int lane, int wv,
                                              f32x4 acc[][2]) {
  constexpr int WT = NG * 1024;
  const u16* Wp = A + 16384;
#pragma unroll
  for (int kk = 0; kk < 2; ++kk) {
    const int sw = (((kk * 4 + (lane >> 4)) ^ (lane & 7)) << 3);
    s16x8 bh[NG], bl[NG];
#pragma unroll
    for (int g = 0; g < NG; ++g) {
      const u16* wp = Wp + (g * 16 + (lane & 15)) * 64 + sw;
      bh[g] = *(const s16x8*)(wp);
      bl[g] = *(const s16x8*)(wp + WT);
    }
#pragma unroll
    for (int mf = 0; mf < 2; ++mf) {
      const u16* ap = A + (wv * 32 + mf * 16 + (lane & 15)) * 64 + sw;
      s16x8 ah = *(const s16x8*)(ap);
      s16x8 al = *(const s16x8*)(ap + 8192);
#pragma unroll
      for (int g = 0; g < NG; ++g) {
        const int q = (NG == 3 && g == 2) ? (SEG1 ? 3 : 2) : g;
        acc[q][mf] = mfma16(ah, bh[g], acc[q][mf]);
        acc[q][mf] = mfma16(al, bh[g], acc[q][mf]);
        acc[q][mf] = mfma16(ah, bl[g], acc[q][mf]);
      }
    }
  }
}

// =====================================================================
// fused split-K GEMM + last-block epilogue
// NG=3 MODE=0: GRU (quantities R,Z,IN,HN; epilogue -> h planes)
// NG=1 MODE=1: proj+relu -> p planes ;  MODE=2: out -> y planes + f32 d_out
// grid: dim3(NBLK, 4 slices), 256 threads
// =====================================================================
template<int NG, int MODE>
__global__ __launch_bounds__(256)
void fused_gemm(const u16* __restrict__ a0, const u16* __restrict__ w0, int nc0,
                const u16* __restrict__ a1, const u16* __restrict__ w1, int nc1,
                float* __restrict__ P, int* __restrict__ ctr,
                const float* __restrict__ bias0, const float* __restrict__ bias1,
                const u16* __restrict__ hprev, u16* __restrict__ oplanes,
                float* __restrict__ yout) {
  constexpr int WT = NG * 1024;
  constexpr int BUFU = 16384 + 2 * WT;
  constexpr int NQ = (NG == 3) ? 4 : 1;
  __shared__ u16 sm[2 * BUFU];
  __shared__ int lastflag;

  const int tid = threadIdx.x;
  const int lane = tid & 63;
  const int wv = tid >> 6;
  const int cb = blockIdx.x;
  const int sl = blockIdx.y;
  const int NC = nc0 + nc1;
  const int c0 = (sl * NC) >> 2;
  const int c1 = ((sl + 1) * NC) >> 2;

  f32x4 acc[NQ][2];
#pragma unroll
  for (int q = 0; q < NQ; ++q) {
    acc[q][0] = f32x4{0.f, 0.f, 0.f, 0.f};
    acc[q][1] = f32x4{0.f, 0.f, 0.f, 0.f};
  }

  auto stage = [&](int c, int buf) {
    const u16 *at, *wt;
    if (c < nc0) { at = a0 + (size_t)c * 16384; wt = w0 + (size_t)(cb * nc0 + c) * (2 * WT); }
    else { int cc = c - nc0; at = a1 + (size_t)cc * 16384; wt = w1 + (size_t)(cb * nc1 + cc) * (2 * WT); }
    u16* sa = sm + buf * BUFU;
    for (int i = wv; i < 32; i += 4)                 // A: 32 KB -> 8 issues/wave
      glds16(sa + i * 512, at + i * 512 + lane * 8);
    u16* swl = sa + 16384;
    for (int i = wv; i < (WT >> 8); i += 4)          // W: GRU 3/wave, LIN 1/wave
      glds16(swl + i * 512, wt + i * 512 + lane * 8);
  };

  stage(c0, 0);
  for (int c = c0; c < c1; ++c) {
    const int buf = (c - c0) & 1;
    if (c + 1 < c1) {
      stage(c + 1, buf ^ 1);                          // prefetch next chunk
      if constexpr (NG == 3) asm volatile("s_waitcnt vmcnt(11)" ::: "memory");
      else                   asm volatile("s_waitcnt vmcnt(9)" ::: "memory");
    } else {
      asm volatile("s_waitcnt vmcnt(0)" ::: "memory");
    }
    __builtin_amdgcn_s_barrier();
    asm volatile("" ::: "memory");
    const u16* A = sm + buf * BUFU;
    if (c < nc0) compute_chunk<NG, false>(A, lane, wv, acc);
    else         compute_chunk<NG, true>(A, lane, wv, acc);
    asm volatile("s_waitcnt lgkmcnt(0)" ::: "memory");
    __builtin_amdgcn_s_barrier();
    asm volatile("" ::: "memory");
  }

  // ---- write slice partials ----
  {
    float* Pb = P + (size_t)(cb * 4 + sl) * (NQ * 2048);
#pragma unroll
    for (int q = 0; q < NQ; ++q)
#pragma unroll
      for (int mf = 0; mf < 2; ++mf)
#pragma unroll
        for (int e = 0; e < 4; ++e) {
          int row = wv * 32 + mf * 16 + (lane >> 4) * 4 + e;
          Pb[q * 2048 + row * 16 + (lane & 15)] = acc[q][mf][e];
        }
  }
  __threadfence();
  __syncthreads();
  if (tid == 0) lastflag = (atomicAdd(ctr + cb, 1) == 3) ? 1 : 0;
  __syncthreads();
  if (!lastflag) return;
  __threadfence();

  // ---- last block: reduce slices + epilogue ----
  const int c16 = tid & 15;
  const int rg = tid >> 4;
  const int j = cb * 16 + c16;

  if constexpr (MODE == 0) {
    const float b_r = bias0[j] + bias1[j];
    const float b_z = bias0[Hdim + j] + bias1[Hdim + j];
    const float b_in = bias0[2 * Hdim + j];
    const float b_hn = bias1[2 * Hdim + j];
    const int ch = j >> 6, k6 = j & 63;
#pragma unroll
    for (int e = 0; e < 8; ++e) {
      const int r = rg + e * 16;
      float s0 = 0.f, s1 = 0.f, s2 = 0.f, s3 = 0.f;
#pragma unroll
      for (int s = 0; s < 4; ++s) {
        const float* Ps = P + (size_t)(cb * 4 + s) * 8192 + r * 16 + c16;
        s0 += Ps[0]; s1 += Ps[2048]; s2 += Ps[4096]; s3 += Ps[6144];
      }
      const float rr = 1.f / (1.f + expf(-(s0 + b_r)));
      const float zz = 1.f / (1.f + expf(-(s1 + b_z)));
      const int o = ch * 16384 + r * 64 + swz8(r, k6 >> 3) + (k6 & 7);
      const float hp = bf2f(hprev[o]) + bf2f(hprev[o + 8192]);
      const float nn = tanhf(s2 + b_in + rr * (s3 + b_hn));
      const float h = (1.f - zz) * nn + zz * hp;
      const u16 hh = f2bf(h);
      oplanes[o] = hh;
      oplanes[o + 8192] = f2bf(h - bf2f(hh));
    }
  } else {
#pragma unroll
    for (int e = 0; e < 8; ++e) {
      const int r = rg + e * 16;
      float s0 = 0.f;
#pragma unroll
      for (int s = 0; s < 4; ++s)
        s0 += P[(size_t)(cb * 4 + s) * 2048 + r * 16 + c16];
      float v = s0 + bias0[j];
      if constexpr (MODE == 1) v = fmaxf(v, 0.f);
      const int ch = j >> 6, k6 = j & 63;
      const int o = ch * 16384 + r * 64 + swz8(r, k6 >> 3) + (k6 & 7);
      const u16 hh = f2bf(v);
      oplanes[o] = hh;
      oplanes[o + 8192] = f2bf(v - bf2f(hh));
      if constexpr (MODE == 2) yout[(size_t)r * (OUTLEN * Fdim) + j] = v;
    }
  }
}

// =====================================================================
extern "C" void kernel_launch(void* const* d_in, const int* in_sizes, int n_in,
                              void* d_out, int out_size, void* d_ws, size_t ws_size,
                              hipStream_t stream) {
  const float* X     = (const float*)d_in[0];
  const float* eWih0 = (const float*)d_in[1];
  const float* eWhh0 = (const float*)d_in[2];
  const float* ebih0 = (const float*)d_in[3];
  const float* ebhh0 = (const float*)d_in[4];
  const float* eWih1 = (const float*)d_in[5];
  const float* eWhh1 = (const float*)d_in[6];
  const float* ebih1 = (const float*)d_in[7];
  const float* ebhh1 = (const float*)d_in[8];
  const float* dWih0 = (const float*)d_in[9];
  const float* dWhh0 = (const float*)d_in[10];
  const float* dbih0 = (const float*)d_in[11];
  const float* dbhh0 = (const float*)d_in[12];
  const float* dWih1 = (const float*)d_in[13];
  const float* dWhh1 = (const float*)d_in[14];
  const float* dbih1 = (const float*)d_in[15];
  const float* dbhh1 = (const float*)d_in[16];
  const float* projW = (const float*)d_in[17];
  const float* projb = (const float*)d_in[18];
  const float* outW  = (const float*)d_in[19];
  const float* outb  = (const float*)d_in[20];
  float* outf = (float*)d_out;

  u16* wsp = (u16*)d_ws;
  size_t off = 0;
  auto take = [&](size_t n) { u16* p = wsp + off; off += n; return p; };

  u16* pl_eWih0 = take(64ULL * 1 * 2 * 48 * 64);
  u16* pl_eWhh0 = take(64ULL * 16 * 2 * 48 * 64);
  u16* pl_eWih1 = take(64ULL * 16 * 2 * 48 * 64);
  u16* pl_eWhh1 = take(64ULL * 16 * 2 * 48 * 64);
  u16* pl_dWih0 = take(64ULL * 1 * 2 * 48 * 64);
  u16* pl_dWhh0 = take(64ULL * 16 * 2 * 48 * 64);
  u16* pl_dWih1 = take(64ULL * 16 * 2 * 48 * 64);
  u16* pl_dWhh1 = take(64ULL * 16 * 2 * 48 * 64);
  u16* pl_proj  = take(32ULL * 16 * 2 * 16 * 64);
  u16* pl_out   = take(4ULL * 8 * 2 * 16 * 64);
  u16* pl_x     = take(256ULL * 2 * 128 * 64);
  u16* pl_h0    = take(2ULL * 16 * 2 * 128 * 64);   // 2 slots, stride 262144
  u16* pl_h1    = take(2ULL * 16 * 2 * 128 * 64);
  u16* pl_y     = take(2ULL * 1 * 2 * 128 * 64);    // 2 slots, stride 16384
  u16* pl_p     = take(8ULL * 2 * 128 * 64);
  float* Pbuf   = (float*)take(4194304);            // 2,097,152 f32
  int* ctrs     = (int*)take(90112);                // 45,056 int
  if (off * 2 > ws_size) return;                    // scratch too small -> loud fail

  hipMemsetAsync(pl_h0, 0, 262144 * 2, stream);     // h0 slot0 = 0
  hipMemsetAsync(pl_h1, 0, 262144 * 2, stream);     // h1 slot0 = 0
  hipMemsetAsync(ctrs, 0, 45056 * 4, stream);

  auto pw = [&](const float* W, u16* dst, int colblks, int nc, int rows, int K, int gru) {
    int total = colblks * nc * rows * 8;
    prep_w<<<(total + 255) / 256, 256, 0, stream>>>(W, dst, colblks, nc, rows, K, gru);
  };
  pw(eWih0, pl_eWih0, 64, 1, 48, 64, 1);
  pw(eWhh0, pl_eWhh0, 64, 16, 48, 1024, 1);
  pw(eWih1, pl_eWih1, 64, 16, 48, 1024, 1);
  pw(eWhh1, pl_eWhh1, 64, 16, 48, 1024, 1);
  pw(dWih0, pl_dWih0, 64, 1, 48, 64, 1);
  pw(dWhh0, pl_dWhh0, 64, 16, 48, 1024, 1);
  pw(dWih1, pl_dWih1, 64, 16, 48, 1024, 1);
  pw(dWhh1, pl_dWhh1, 64, 16, 48, 1024, 1);
  pw(projW, pl_proj, 32, 16, 16, 1024, 0);
  pw(outW,  pl_out,  4,  8,  16, 512, 0);
  prep_x<<<1024, 256, 0, stream>>>(X, pl_x);

  int invok = 0;
  auto gru = [&](const u16* a0, const u16* w0, int nc0, u16* hin, const u16* whh,
                 const float* bih, const float* bhh, u16* hout) {
    fused_gemm<3, 0><<<dim3(64, 4), 256, 0, stream>>>(
        a0, w0, nc0, hin, whh, 16, Pbuf, ctrs + 64 * invok, bih, bhh, hin, hout, nullptr);
    ++invok;
  };

  // ---------------- encoder ----------------
  for (int t = 0; t < Tdim; ++t) {
    u16* h0i = pl_h0 + (t & 1) * 262144;
    u16* h0o = pl_h0 + ((t + 1) & 1) * 262144;
    u16* h1i = pl_h1 + (t & 1) * 262144;
    u16* h1o = pl_h1 + ((t + 1) & 1) * 262144;
    gru(pl_x + (size_t)t * 16384, pl_eWih0, 1, h0i, pl_eWhh0, ebih0, ebhh0, h0o);
    gru(h0o, pl_eWih1, 16, h1i, pl_eWhh1, ebih1, ebhh1, h1o);
  }

  // ---------------- decoder ----------------
  for (int s = 0; s < OUTLEN; ++s) {
    const u16* xs = (s == 0) ? (pl_x + 255ULL * 16384) : (pl_y + ((s - 1) & 1) * 16384);
    u16* h0i = pl_h0 + (s & 1) * 262144;
    u16* h0o = pl_h0 + ((s + 1) & 1) * 262144;
    u16* h1i = pl_h1 + (s & 1) * 262144;
    u16* h1o = pl_h1 + ((s + 1) & 1) * 262144;
    gru(xs, pl_dWih0, 1, h0i, pl_dWhh0, dbih0, dbhh0, h0o);
    gru(h0o, pl_dWih1, 16, h1i, pl_dWhh1, dbih1, dbhh1, h1o);
    fused_gemm<1, 1><<<dim3(32, 4), 256, 0, stream>>>(
        h1o, pl_proj, 16, nullptr, nullptr, 0, Pbuf, ctrs + 64 * invok, projb, nullptr,
        nullptr, pl_p, nullptr);
    ++invok;
    fused_gemm<1, 2><<<dim3(4, 4), 256, 0, stream>>>(
        pl_p, pl_out, 8, nullptr, nullptr, 0, Pbuf, ctrs + 64 * invok, outb, nullptr,
        nullptr, pl_y + (s & 1) * 16384, outf + (size_t)s * 64);
    ++invok;
  }
}

// Round 7
// 18475.467 us; speedup vs baseline: 3.8644x; 1.6625x over previous
//
#include <hip/hip_runtime.h>

#define Bdim 128
#define Tdim 256
#define Fdim 64
#define Hdim 1024
#define Pdim 512
#define OUTLEN 48

typedef float  f32x4 __attribute__((ext_vector_type(4)));
typedef short  s16x8 __attribute__((ext_vector_type(8)));
typedef unsigned short u16;

__device__ __forceinline__ u16 f2bf(float f) {
  unsigned u = __float_as_uint(f);
  u += 0x7FFFu + ((u >> 16) & 1u);   // RNE
  return (u16)(u >> 16);
}
__device__ __forceinline__ float bf2f(u16 s) { return __uint_as_float(((unsigned)s) << 16); }
// 16B-block XOR swizzle within a 128B row (G4 pattern); returns u16 offset of block
__device__ __forceinline__ int swz8(int row, int blk) { return ((blk ^ (row & 7)) << 3); }

__device__ __forceinline__ f32x4 mfma16(s16x8 a, s16x8 b, f32x4 c) {
  return __builtin_amdgcn_mfma_f32_16x16x32_bf16(a, b, c, 0, 0, 0);
}

// async global->LDS, 16B per lane; lds base must be wave-uniform (HW adds lane*16)
__device__ __forceinline__ void glds16(u16* lds, const u16* g) {
  __builtin_amdgcn_global_load_lds(
      (const __attribute__((address_space(1))) unsigned int*)g,
      (__attribute__((address_space(3))) unsigned int*)lds, 16, 0, 0);
}

// =====================================================================
// prep: fp32 weight [N][K] -> swizzled bf16 hi/lo plane tiles
// layout: [colblk][nc][2(hi,lo)][rows][64]  (rows = 48 gru / 16 lin)
// =====================================================================
__global__ __launch_bounds__(256)
void prep_w(const float* __restrict__ W, u16* __restrict__ dst,
            int colblks, int nc, int rows, int K, int gru) {
  int idx = blockIdx.x * 256 + threadIdx.x;
  if (idx >= colblks * nc * rows * 8) return;
  int blk = idx & 7;
  int t = idx >> 3;
  int r = t % rows; t /= rows;
  int c = t % nc;
  int cb = t / nc;
  int srow = gru ? ((r >> 4) * Hdim + cb * 16 + (r & 15)) : (cb * 16 + r);
  const float* src = W + (size_t)srow * K + c * 64 + blk * 8;
  s16x8 vh, vl;
#pragma unroll
  for (int e = 0; e < 8; ++e) {
    float v = src[e];
    u16 h = f2bf(v);
    vh[e] = (short)h;
    vl[e] = (short)f2bf(v - bf2f(h));
  }
  size_t tb = (size_t)(cb * nc + c) * (2 * rows * 64);
  int o = r * 64 + swz8(r, blk);
  *(s16x8*)(dst + tb + o) = vh;
  *(s16x8*)(dst + tb + (size_t)rows * 64 + o) = vl;
}

// X [128][256][64] fp32 -> per-t A-tiles [256][2][128][64]
__global__ __launch_bounds__(256)
void prep_x(const float* __restrict__ X, u16* __restrict__ dst) {
  int idx = blockIdx.x * 256 + threadIdx.x;   // 256*128*8
  int blk = idx & 7;
  int row = (idx >> 3) & 127;
  int t = idx >> 10;
  const float* src = X + (size_t)row * (Tdim * Fdim) + t * 64 + blk * 8;
  s16x8 vh, vl;
#pragma unroll
  for (int e = 0; e < 8; ++e) {
    float v = src[e];
    u16 h = f2bf(v);
    vh[e] = (short)h;
    vl[e] = (short)f2bf(v - bf2f(h));
  }
  size_t tb = (size_t)t * 16384;
  int o = row * 64 + swz8(row, blk);
  *(s16x8*)(dst + tb + o) = vh;
  *(s16x8*)(dst + tb + 8192 + o) = vl;
}

// =====================================================================
// one staged 64-k chunk of MFMA work (3-term hi/lo split) — r3-verbatim:
// LDS: A hi[128][64] (8192 u16) | A lo (8192) | W hi[NG*16][64] | W lo
// =====================================================================
template<int NG, bool SEG1>
__device__ __forceinline__ void compute_chunk(const u16* __restrict__ A, int lane, int wv,
                                              f32x4 acc[][2]) {
  constexpr int WT = NG * 1024;
  const u16* Wp = A + 16384;
#pragma unroll
  for (int kk = 0; kk < 2; ++kk) {
    const int sw = (((kk * 4 + (lane >> 4)) ^ (lane & 7)) << 3);
    s16x8 bh[NG], bl[NG];
#pragma unroll
    for (int g = 0; g < NG; ++g) {
      const u16* wp = Wp + (g * 16 + (lane & 15)) * 64 + sw;
      bh[g] = *(const s16x8*)(wp);
      bl[g] = *(const s16x8*)(wp + WT);
    }
#pragma unroll
    for (int mf = 0; mf < 2; ++mf) {
      const u16* ap = A + (wv * 32 + mf * 16 + (lane & 15)) * 64 + sw;
      s16x8 ah = *(const s16x8*)(ap);
      s16x8 al = *(const s16x8*)(ap + 8192);
#pragma unroll
      for (int g = 0; g < NG; ++g) {
        const int q = (NG == 3 && g == 2) ? (SEG1 ? 3 : 2) : g;
        acc[q][mf] = mfma16(ah, bh[g], acc[q][mf]);
        acc[q][mf] = mfma16(al, bh[g], acc[q][mf]);
        acc[q][mf] = mfma16(ah, bl[g], acc[q][mf]);
      }
    }
  }
}

// =====================================================================
// fused GEMM, full-K per block, direct register epilogue.
// No inter-block communication of any kind.
// NG=3 MODE=0: GRU (R,Z,IN,HN; epilogue -> h planes); grid 64 blocks
// NG=1 MODE=1: proj+relu -> p planes (grid 32); MODE=2: out -> y + f32 (grid 4)
// =====================================================================
template<int NG, int MODE>
__global__ __launch_bounds__(256)
void fused_gemm(const u16* __restrict__ a0, const u16* __restrict__ w0, int nc0,
                const u16* __restrict__ a1, const u16* __restrict__ w1, int nc1,
                const float* __restrict__ bias0, const float* __restrict__ bias1,
                const u16* __restrict__ hprev, u16* __restrict__ oplanes,
                float* __restrict__ yout) {
  constexpr int WT = NG * 1024;            // u16 per W plane tile
  constexpr int BUFU = 16384 + 2 * WT;     // full A (hi+lo) + W (hi+lo)
  constexpr int NQ = (NG == 3) ? 4 : 1;
  __shared__ u16 sm[2 * BUFU];

  const int tid = threadIdx.x;
  const int lane = tid & 63;
  const int wv = tid >> 6;
  const int cb = blockIdx.x;
  const int NC = nc0 + nc1;

  f32x4 acc[NQ][2];
#pragma unroll
  for (int q = 0; q < NQ; ++q) {
    acc[q][0] = f32x4{0.f, 0.f, 0.f, 0.f};
    acc[q][1] = f32x4{0.f, 0.f, 0.f, 0.f};
  }

  auto stage = [&](int c, int buf) {
    const u16 *at, *wt;
    if (c < nc0) { at = a0 + (size_t)c * 16384; wt = w0 + (size_t)(cb * nc0 + c) * (2 * WT); }
    else { int cc = c - nc0; at = a1 + (size_t)cc * 16384; wt = w1 + (size_t)(cb * nc1 + cc) * (2 * WT); }
    u16* sa = sm + buf * BUFU;
    for (int i = wv; i < 32; i += 4)                 // A: 32 KB -> 8 issues/wave
      glds16(sa + i * 512, at + i * 512 + lane * 8);
    u16* swl = sa + 16384;
    for (int i = wv; i < (WT >> 8); i += 4)          // W: GRU 3/wave, LIN 1/wave
      glds16(swl + i * 512, wt + i * 512 + lane * 8);
  };

  stage(0, 0);
  for (int c = 0; c < NC; ++c) {
    const int buf = c & 1;
    if (c + 1 < NC) {
      stage(c + 1, buf ^ 1);                          // prefetch next chunk
      if constexpr (NG == 3) asm volatile("s_waitcnt vmcnt(11)" ::: "memory");
      else                   asm volatile("s_waitcnt vmcnt(9)" ::: "memory");
    } else {
      asm volatile("s_waitcnt vmcnt(0)" ::: "memory");
    }
    __builtin_amdgcn_s_barrier();
    asm volatile("" ::: "memory");
    const u16* A = sm + buf * BUFU;
    if (c < nc0) compute_chunk<NG, false>(A, lane, wv, acc);
    else         compute_chunk<NG, true>(A, lane, wv, acc);
    asm volatile("s_waitcnt lgkmcnt(0)" ::: "memory");
    __builtin_amdgcn_s_barrier();
    asm volatile("" ::: "memory");
  }

  // ---- direct epilogue (C layout: col=lane&15, row=wv*32+mf*16+(lane>>4)*4+e) ----
  const int j = cb * 16 + (lane & 15);
  const int ch = j >> 6, k6 = j & 63;

  if constexpr (MODE == 0) {
    const float b_r = bias0[j] + bias1[j];
    const float b_z = bias0[Hdim + j] + bias1[Hdim + j];
    const float b_in = bias0[2 * Hdim + j];
    const float b_hn = bias1[2 * Hdim + j];
#pragma unroll
    for (int mf = 0; mf < 2; ++mf) {
#pragma unroll
      for (int e = 0; e < 4; ++e) {
        const int r = wv * 32 + mf * 16 + (lane >> 4) * 4 + e;
        const int o = ch * 16384 + r * 64 + swz8(r, k6 >> 3) + (k6 & 7);
        const float hp = bf2f(hprev[o]) + bf2f(hprev[o + 8192]);
        const float rr = 1.f / (1.f + expf(-(acc[0][mf][e] + b_r)));
        const float zz = 1.f / (1.f + expf(-(acc[1][mf][e] + b_z)));
        const float nn = tanhf(acc[2][mf][e] + b_in + rr * (acc[3][mf][e] + b_hn));
        const float h = (1.f - zz) * nn + zz * hp;
        const u16 hh = f2bf(h);
        oplanes[o] = hh;
        oplanes[o + 8192] = f2bf(h - bf2f(hh));
      }
    }
  } else {
    const float bb = bias0[j];
#pragma unroll
    for (int mf = 0; mf < 2; ++mf) {
#pragma unroll
      for (int e = 0; e < 4; ++e) {
        const int r = wv * 32 + mf * 16 + (lane >> 4) * 4 + e;
        float v = acc[0][mf][e] + bb;
        if constexpr (MODE == 1) v = fmaxf(v, 0.f);
        const int o = ch * 16384 + r * 64 + swz8(r, k6 >> 3) + (k6 & 7);
        const u16 hh = f2bf(v);
        oplanes[o] = hh;
        oplanes[o + 8192] = f2bf(v - bf2f(hh));
        if constexpr (MODE == 2) yout[(size_t)r * (OUTLEN * Fdim) + j] = v;
      }
    }
  }
}

// =====================================================================
extern "C" void kernel_launch(void* const* d_in, const int* in_sizes, int n_in,
                              void* d_out, int out_size, void* d_ws, size_t ws_size,
                              hipStream_t stream) {
  const float* X     = (const float*)d_in[0];
  const float* eWih0 = (const float*)d_in[1];
  const float* eWhh0 = (const float*)d_in[2];
  const float* ebih0 = (const float*)d_in[3];
  const float* ebhh0 = (const float*)d_in[4];
  const float* eWih1 = (const float*)d_in[5];
  const float* eWhh1 = (const float*)d_in[6];
  const float* ebih1 = (const float*)d_in[7];
  const float* ebhh1 = (const float*)d_in[8];
  const float* dWih0 = (const float*)d_in[9];
  const float* dWhh0 = (const float*)d_in[10];
  const float* dbih0 = (const float*)d_in[11];
  const float* dbhh0 = (const float*)d_in[12];
  const float* dWih1 = (const float*)d_in[13];
  const float* dWhh1 = (const float*)d_in[14];
  const float* dbih1 = (const float*)d_in[15];
  const float* dbhh1 = (const float*)d_in[16];
  const float* projW = (const float*)d_in[17];
  const float* projb = (const float*)d_in[18];
  const float* outW  = (const float*)d_in[19];
  const float* outb  = (const float*)d_in[20];
  float* outf = (float*)d_out;

  u16* wsp = (u16*)d_ws;
  size_t off = 0;
  auto take = [&](size_t n) { u16* p = wsp + off; off += n; return p; };

  u16* pl_eWih0 = take(64ULL * 1 * 2 * 48 * 64);
  u16* pl_eWhh0 = take(64ULL * 16 * 2 * 48 * 64);
  u16* pl_eWih1 = take(64ULL * 16 * 2 * 48 * 64);
  u16* pl_eWhh1 = take(64ULL * 16 * 2 * 48 * 64);
  u16* pl_dWih0 = take(64ULL * 1 * 2 * 48 * 64);
  u16* pl_dWhh0 = take(64ULL * 16 * 2 * 48 * 64);
  u16* pl_dWih1 = take(64ULL * 16 * 2 * 48 * 64);
  u16* pl_dWhh1 = take(64ULL * 16 * 2 * 48 * 64);
  u16* pl_proj  = take(32ULL * 16 * 2 * 16 * 64);
  u16* pl_out   = take(4ULL * 8 * 2 * 16 * 64);
  u16* pl_x     = take(256ULL * 2 * 128 * 64);
  u16* pl_h0    = take(2ULL * 16 * 2 * 128 * 64);   // 2 slots, stride 262144
  u16* pl_h1    = take(2ULL * 16 * 2 * 128 * 64);
  u16* pl_y     = take(2ULL * 1 * 2 * 128 * 64);    // 2 slots, stride 16384
  u16* pl_p     = take(8ULL * 2 * 128 * 64);
  if (off * 2 > ws_size) return;                    // scratch too small -> loud fail

  hipMemsetAsync(pl_h0, 0, 262144 * 2, stream);     // h0 slot0 = 0
  hipMemsetAsync(pl_h1, 0, 262144 * 2, stream);     // h1 slot0 = 0

  auto pw = [&](const float* W, u16* dst, int colblks, int nc, int rows, int K, int gru) {
    int total = colblks * nc * rows * 8;
    prep_w<<<(total + 255) / 256, 256, 0, stream>>>(W, dst, colblks, nc, rows, K, gru);
  };
  pw(eWih0, pl_eWih0, 64, 1, 48, 64, 1);
  pw(eWhh0, pl_eWhh0, 64, 16, 48, 1024, 1);
  pw(eWih1, pl_eWih1, 64, 16, 48, 1024, 1);
  pw(eWhh1, pl_eWhh1, 64, 16, 48, 1024, 1);
  pw(dWih0, pl_dWih0, 64, 1, 48, 64, 1);
  pw(dWhh0, pl_dWhh0, 64, 16, 48, 1024, 1);
  pw(dWih1, pl_dWih1, 64, 16, 48, 1024, 1);
  pw(dWhh1, pl_dWhh1, 64, 16, 48, 1024, 1);
  pw(projW, pl_proj, 32, 16, 16, 1024, 0);
  pw(outW,  pl_out,  4,  8,  16, 512, 0);
  prep_x<<<1024, 256, 0, stream>>>(X, pl_x);

  // nc0 MUST be threaded through: 1 for x-input (K=64), 16 for h-input (K=1024).
  // (r5/r6 hardcoded 1 here -> layer-1 GRU used 1/16 of its input. Identical
  //  absmax across two different kernels was the tell.)
  auto gru = [&](const u16* a0, const u16* w0, int nc0, const u16* hin, const u16* whh,
                 const float* bih, const float* bhh, u16* hout) {
    fused_gemm<3, 0><<<64, 256, 0, stream>>>(
        a0, w0, nc0, hin, whh, 16, bih, bhh, hin, hout, nullptr);
  };

  // ---------------- encoder ----------------
  for (int t = 0; t < Tdim; ++t) {
    u16* h0i = pl_h0 + (t & 1) * 262144;
    u16* h0o = pl_h0 + ((t + 1) & 1) * 262144;
    u16* h1i = pl_h1 + (t & 1) * 262144;
    u16* h1o = pl_h1 + ((t + 1) & 1) * 262144;
    gru(pl_x + (size_t)t * 16384, pl_eWih0, 1, h0i, pl_eWhh0, ebih0, ebhh0, h0o);
    gru(h0o, pl_eWih1, 16, h1i, pl_eWhh1, ebih1, ebhh1, h1o);
  }

  // ---------------- decoder ----------------
  for (int s = 0; s < OUTLEN; ++s) {
    const u16* xs = (s == 0) ? (pl_x + 255ULL * 16384) : (pl_y + ((s - 1) & 1) * 16384);
    u16* h0i = pl_h0 + (s & 1) * 262144;
    u16* h0o = pl_h0 + ((s + 1) & 1) * 262144;
    u16* h1i = pl_h1 + (s & 1) * 262144;
    u16* h1o = pl_h1 + ((s + 1) & 1) * 262144;
    gru(xs, pl_dWih0, 1, h0i, pl_dWhh0, dbih0, dbhh0, h0o);
    gru(h0o, pl_dWih1, 16, h1i, pl_dWhh1, dbih1, dbhh1, h1o);
    fused_gemm<1, 1><<<32, 256, 0, stream>>>(
        h1o, pl_proj, 16, nullptr, nullptr, 0, projb, nullptr,
        nullptr, pl_p, nullptr);
    fused_gemm<1, 2><<<4, 256, 0, stream>>>(
        pl_p, pl_out, 8, nullptr, nullptr, 0, outb, nullptr,
        nullptr, pl_y + (s & 1) * 16384, outf + (size_t)s * 64);
  }
}

// Round 8
// 13232.359 us; speedup vs baseline: 5.3956x; 1.3962x over previous
//
#include <hip/hip_runtime.h>

#define Bdim 128
#define Tdim 256
#define Fdim 64
#define Hdim 1024
#define Pdim 512
#define OUTLEN 48

typedef float  f32x4 __attribute__((ext_vector_type(4)));
typedef short  s16x8 __attribute__((ext_vector_type(8)));
typedef unsigned short u16;

__device__ __forceinline__ u16 f2bf(float f) {
  unsigned u = __float_as_uint(f);
  u += 0x7FFFu + ((u >> 16) & 1u);   // RNE
  return (u16)(u >> 16);
}
__device__ __forceinline__ float bf2f(u16 s) { return __uint_as_float(((unsigned)s) << 16); }
// 16B-block XOR swizzle within a 128B row (G4 pattern); returns u16 offset of block
__device__ __forceinline__ int swz8(int row, int blk) { return ((blk ^ (row & 7)) << 3); }

__device__ __forceinline__ f32x4 mfma16(s16x8 a, s16x8 b, f32x4 c) {
  return __builtin_amdgcn_mfma_f32_16x16x32_bf16(a, b, c, 0, 0, 0);
}

// async global->LDS, 16B per lane; lds base must be wave-uniform (HW adds lane*16)
__device__ __forceinline__ void glds16(u16* lds, const u16* g) {
  __builtin_amdgcn_global_load_lds(
      (const __attribute__((address_space(1))) unsigned int*)g,
      (__attribute__((address_space(3))) unsigned int*)lds, 16, 0, 0);
}

// =====================================================================
// prep: fp32 weight [N][K] -> swizzled bf16 hi/lo plane tiles
// layout: [colblk][nc][2(hi,lo)][rows][64]  (rows = 48 gru / 16 lin)
// =====================================================================
__global__ __launch_bounds__(256)
void prep_w(const float* __restrict__ W, u16* __restrict__ dst,
            int colblks, int nc, int rows, int K, int gru) {
  int idx = blockIdx.x * 256 + threadIdx.x;
  if (idx >= colblks * nc * rows * 8) return;
  int blk = idx & 7;
  int t = idx >> 3;
  int r = t % rows; t /= rows;
  int c = t % nc;
  int cb = t / nc;
  int srow = gru ? ((r >> 4) * Hdim + cb * 16 + (r & 15)) : (cb * 16 + r);
  const float* src = W + (size_t)srow * K + c * 64 + blk * 8;
  s16x8 vh, vl;
#pragma unroll
  for (int e = 0; e < 8; ++e) {
    float v = src[e];
    u16 h = f2bf(v);
    vh[e] = (short)h;
    vl[e] = (short)f2bf(v - bf2f(h));
  }
  size_t tb = (size_t)(cb * nc + c) * (2 * rows * 64);
  int o = r * 64 + swz8(r, blk);
  *(s16x8*)(dst + tb + o) = vh;
  *(s16x8*)(dst + tb + (size_t)rows * 64 + o) = vl;
}

// X [128][256][64] fp32 -> per-t A-tiles [256][2][128][64]
__global__ __launch_bounds__(256)
void prep_x(const float* __restrict__ X, u16* __restrict__ dst) {
  int idx = blockIdx.x * 256 + threadIdx.x;   // 256*128*8
  int blk = idx & 7;
  int row = (idx >> 3) & 127;
  int t = idx >> 10;
  const float* src = X + (size_t)row * (Tdim * Fdim) + t * 64 + blk * 8;
  s16x8 vh, vl;
#pragma unroll
  for (int e = 0; e < 8; ++e) {
    float v = src[e];
    u16 h = f2bf(v);
    vh[e] = (short)h;
    vl[e] = (short)f2bf(v - bf2f(h));
  }
  size_t tb = (size_t)t * 16384;
  int o = row * 64 + swz8(row, blk);
  *(s16x8*)(dst + tb + o) = vh;
  *(s16x8*)(dst + tb + 8192 + o) = vl;
}

// =====================================================================
// one staged 64-k chunk of MFMA work (3-term hi/lo split) — r3-verbatim:
// LDS: A hi[128][64] (8192 u16) | A lo (8192) | W hi[NG*16][64] | W lo
// =====================================================================
template<int NG, bool SEG1>
__device__ __forceinline__ void compute_chunk(const u16* __restrict__ A, int lane, int wv,
                                              f32x4 acc[][2]) {
  constexpr int WT = NG * 1024;
  const u16* Wp = A + 16384;
#pragma unroll
  for (int kk = 0; kk < 2; ++kk) {
    const int sw = (((kk * 4 + (lane >> 4)) ^ (lane & 7)) << 3);
    s16x8 bh[NG], bl[NG];
#pragma unroll
    for (int g = 0; g < NG; ++g) {
      const u16* wp = Wp + (g * 16 + (lane & 15)) * 64 + sw;
      bh[g] = *(const s16x8*)(wp);
      bl[g] = *(const s16x8*)(wp + WT);
    }
#pragma unroll
    for (int mf = 0; mf < 2; ++mf) {
      const u16* ap = A + (wv * 32 + mf * 16 + (lane & 15)) * 64 + sw;
      s16x8 ah = *(const s16x8*)(ap);
      s16x8 al = *(const s16x8*)(ap + 8192);
#pragma unroll
      for (int g = 0; g < NG; ++g) {
        const int q = (NG == 3 && g == 2) ? (SEG1 ? 3 : 2) : g;
        acc[q][mf] = mfma16(ah, bh[g], acc[q][mf]);
        acc[q][mf] = mfma16(al, bh[g], acc[q][mf]);
        acc[q][mf] = mfma16(ah, bl[g], acc[q][mf]);
      }
    }
  }
}

// =====================================================================
// argument bundle for one GEMM instance (so two can share a launch)
// =====================================================================
struct GArgs {
  const u16* a0; const u16* w0; int nc0;
  const u16* a1; const u16* w1; int nc1;
  const float* bias0; const float* bias1;
  const u16* hprev; u16* oplanes; float* yout;
};

// =====================================================================
// GEMM body: full-K per block, triple-buffered staging (prefetch depth 2),
// direct register epilogue. No inter-block communication.
// NG=3 MODE=0: GRU (R,Z,IN,HN; epilogue -> h planes); 64 col-blocks
// NG=1 MODE=1: proj+relu -> p planes; MODE=2: out -> y planes + f32 d_out
// =====================================================================
template<int NG, int MODE>
__device__ __forceinline__ void gemm_body(u16* __restrict__ sm, const GArgs& g, int cb) {
  constexpr int WT = NG * 1024;            // u16 per W plane tile
  constexpr int BUFU = 16384 + 2 * WT;     // full A (hi+lo) + W (hi+lo)
  constexpr int NQ = (NG == 3) ? 4 : 1;

  const int tid = threadIdx.x;
  const int lane = tid & 63;
  const int wv = tid >> 6;
  const int nc0 = g.nc0;
  const int NC = nc0 + g.nc1;

  f32x4 acc[NQ][2];
#pragma unroll
  for (int q = 0; q < NQ; ++q) {
    acc[q][0] = f32x4{0.f, 0.f, 0.f, 0.f};
    acc[q][1] = f32x4{0.f, 0.f, 0.f, 0.f};
  }

  auto stage = [&](int c, int buf) {
    const u16 *at, *wt;
    if (c < nc0) { at = g.a0 + (size_t)c * 16384; wt = g.w0 + (size_t)(cb * nc0 + c) * (2 * WT); }
    else { int cc = c - nc0; at = g.a1 + (size_t)cc * 16384; wt = g.w1 + (size_t)(cb * g.nc1 + cc) * (2 * WT); }
    u16* sa = sm + buf * BUFU;
    for (int i = wv; i < 32; i += 4)                 // A: 32 KB -> 8 issues/wave
      glds16(sa + i * 512, at + i * 512 + lane * 8);
    u16* swl = sa + 16384;
    for (int i = wv; i < (WT >> 8); i += 4)          // W: GRU 3/wave, LIN 1/wave
      glds16(swl + i * 512, wt + i * 512 + lane * 8);
  };
  // per-wave issues per stage: A=8 + W=(WT>>8)/4 -> 11 (GRU) / 9 (linear)

  stage(0, 0);
  if (NC > 1) stage(1, 1);
  for (int c = 0; c < NC; ++c) {
    if (c + 2 < NC) stage(c + 2, (c + 2) % 3);       // prefetch depth 2
    const int rem = NC - 1 - c;                       // stages newer than c in flight
    if constexpr (NG == 3) {
      if (rem >= 2)      asm volatile("s_waitcnt vmcnt(22)" ::: "memory");
      else if (rem == 1) asm volatile("s_waitcnt vmcnt(11)" ::: "memory");
      else               asm volatile("s_waitcnt vmcnt(0)"  ::: "memory");
    } else {
      if (rem >= 2)      asm volatile("s_waitcnt vmcnt(18)" ::: "memory");
      else if (rem == 1) asm volatile("s_waitcnt vmcnt(9)"  ::: "memory");
      else               asm volatile("s_waitcnt vmcnt(0)"  ::: "memory");
    }
    __builtin_amdgcn_s_barrier();
    asm volatile("" ::: "memory");
    const u16* A = sm + (c % 3) * BUFU;
    if (c < nc0) compute_chunk<NG, false>(A, lane, wv, acc);
    else         compute_chunk<NG, true>(A, lane, wv, acc);
    asm volatile("s_waitcnt lgkmcnt(0)" ::: "memory");
    __builtin_amdgcn_s_barrier();
    asm volatile("" ::: "memory");
  }

  // ---- direct epilogue (C layout: col=lane&15, row=wv*32+mf*16+(lane>>4)*4+e) ----
  const int j = cb * 16 + (lane & 15);
  const int ch = j >> 6, k6 = j & 63;

  if constexpr (MODE == 0) {
    const float b_r = g.bias0[j] + g.bias1[j];
    const float b_z = g.bias0[Hdim + j] + g.bias1[Hdim + j];
    const float b_in = g.bias0[2 * Hdim + j];
    const float b_hn = g.bias1[2 * Hdim + j];
#pragma unroll
    for (int mf = 0; mf < 2; ++mf) {
#pragma unroll
      for (int e = 0; e < 4; ++e) {
        const int r = wv * 32 + mf * 16 + (lane >> 4) * 4 + e;
        const int o = ch * 16384 + r * 64 + swz8(r, k6 >> 3) + (k6 & 7);
        const float hp = bf2f(g.hprev[o]) + bf2f(g.hprev[o + 8192]);
        const float rr = 1.f / (1.f + expf(-(acc[0][mf][e] + b_r)));
        const float zz = 1.f / (1.f + expf(-(acc[1][mf][e] + b_z)));
        const float nn = tanhf(acc[2][mf][e] + b_in + rr * (acc[3][mf][e] + b_hn));
        const float h = (1.f - zz) * nn + zz * hp;
        const u16 hh = f2bf(h);
        g.oplanes[o] = hh;
        g.oplanes[o + 8192] = f2bf(h - bf2f(hh));
      }
    }
  } else {
    const float bb = g.bias0[j];
#pragma unroll
    for (int mf = 0; mf < 2; ++mf) {
#pragma unroll
      for (int e = 0; e < 4; ++e) {
        const int r = wv * 32 + mf * 16 + (lane >> 4) * 4 + e;
        float v = acc[0][mf][e] + bb;
        if constexpr (MODE == 1) v = fmaxf(v, 0.f);
        const int o = ch * 16384 + r * 64 + swz8(r, k6 >> 3) + (k6 & 7);
        const u16 hh = f2bf(v);
        g.oplanes[o] = hh;
        g.oplanes[o + 8192] = f2bf(v - bf2f(hh));
        if constexpr (MODE == 2) g.yout[(size_t)r * (OUTLEN * Fdim) + j] = v;
      }
    }
  }
}

template<int NG, int MODE>
__global__ __launch_bounds__(256)
void fused_gemm(GArgs g) {
  __shared__ u16 sm[3 * (16384 + 2 * NG * 1024)];
  gemm_body<NG, MODE>(sm, g, blockIdx.x);
}

// encoder pair: blocks 0-63 run layer-0 step t, blocks 64-127 run layer-1 step t-1
__global__ __launch_bounds__(256)
void gru_pair(GArgs ga, GArgs gb) {
  __shared__ u16 sm[3 * (16384 + 2 * 3 * 1024)];
  if (blockIdx.x < 64) gemm_body<3, 0>(sm, ga, blockIdx.x);
  else                 gemm_body<3, 0>(sm, gb, blockIdx.x - 64);
}

// =====================================================================
extern "C" void kernel_launch(void* const* d_in, const int* in_sizes, int n_in,
                              void* d_out, int out_size, void* d_ws, size_t ws_size,
                              hipStream_t stream) {
  const float* X     = (const float*)d_in[0];
  const float* eWih0 = (const float*)d_in[1];
  const float* eWhh0 = (const float*)d_in[2];
  const float* ebih0 = (const float*)d_in[3];
  const float* ebhh0 = (const float*)d_in[4];
  const float* eWih1 = (const float*)d_in[5];
  const float* eWhh1 = (const float*)d_in[6];
  const float* ebih1 = (const float*)d_in[7];
  const float* ebhh1 = (const float*)d_in[8];
  const float* dWih0 = (const float*)d_in[9];
  const float* dWhh0 = (const float*)d_in[10];
  const float* dbih0 = (const float*)d_in[11];
  const float* dbhh0 = (const float*)d_in[12];
  const float* dWih1 = (const float*)d_in[13];
  const float* dWhh1 = (const float*)d_in[14];
  const float* dbih1 = (const float*)d_in[15];
  const float* dbhh1 = (const float*)d_in[16];
  const float* projW = (const float*)d_in[17];
  const float* projb = (const float*)d_in[18];
  const float* outW  = (const float*)d_in[19];
  const float* outb  = (const float*)d_in[20];
  float* outf = (float*)d_out;

  u16* wsp = (u16*)d_ws;
  size_t off = 0;
  auto take = [&](size_t n) { u16* p = wsp + off; off += n; return p; };

  u16* pl_eWih0 = take(64ULL * 1 * 2 * 48 * 64);
  u16* pl_eWhh0 = take(64ULL * 16 * 2 * 48 * 64);
  u16* pl_eWih1 = take(64ULL * 16 * 2 * 48 * 64);
  u16* pl_eWhh1 = take(64ULL * 16 * 2 * 48 * 64);
  u16* pl_dWih0 = take(64ULL * 1 * 2 * 48 * 64);
  u16* pl_dWhh0 = take(64ULL * 16 * 2 * 48 * 64);
  u16* pl_dWih1 = take(64ULL * 16 * 2 * 48 * 64);
  u16* pl_dWhh1 = take(64ULL * 16 * 2 * 48 * 64);
  u16* pl_proj  = take(32ULL * 16 * 2 * 16 * 64);
  u16* pl_out   = take(4ULL * 8 * 2 * 16 * 64);
  u16* pl_x     = take(256ULL * 2 * 128 * 64);
  u16* pl_h0    = take(2ULL * 16 * 2 * 128 * 64);   // 2 slots, stride 262144
  u16* pl_h1    = take(2ULL * 16 * 2 * 128 * 64);
  u16* pl_y     = take(2ULL * 1 * 2 * 128 * 64);    // 2 slots, stride 16384
  u16* pl_p     = take(8ULL * 2 * 128 * 64);
  if (off * 2 > ws_size) return;                    // scratch too small -> loud fail

  hipMemsetAsync(pl_h0, 0, 262144 * 2, stream);     // h0 slot0 = 0
  hipMemsetAsync(pl_h1, 0, 262144 * 2, stream);     // h1 slot0 = 0

  auto pw = [&](const float* W, u16* dst, int colblks, int nc, int rows, int K, int gru) {
    int total = colblks * nc * rows * 8;
    prep_w<<<(total + 255) / 256, 256, 0, stream>>>(W, dst, colblks, nc, rows, K, gru);
  };
  pw(eWih0, pl_eWih0, 64, 1, 48, 64, 1);
  pw(eWhh0, pl_eWhh0, 64, 16, 48, 1024, 1);
  pw(eWih1, pl_eWih1, 64, 16, 48, 1024, 1);
  pw(eWhh1, pl_eWhh1, 64, 16, 48, 1024, 1);
  pw(dWih0, pl_dWih0, 64, 1, 48, 64, 1);
  pw(dWhh0, pl_dWhh0, 64, 16, 48, 1024, 1);
  pw(dWih1, pl_dWih1, 64, 16, 48, 1024, 1);
  pw(dWhh1, pl_dWhh1, 64, 16, 48, 1024, 1);
  pw(projW, pl_proj, 32, 16, 16, 1024, 0);
  pw(outW,  pl_out,  4,  8,  16, 512, 0);
  prep_x<<<1024, 256, 0, stream>>>(X, pl_x);

  // nc0 MUST be threaded through: 1 for x-input (K=64), 16 for h-input (K=1024).
  auto mkL0 = [&](int t, const u16* xs, const float* bih, const float* bhh,
                  const u16* wih, const u16* whh) {
    const u16* h0i = pl_h0 + (size_t)(t & 1) * 262144;
    u16* h0o = pl_h0 + (size_t)((t + 1) & 1) * 262144;
    return GArgs{xs, wih, 1, h0i, whh, 16, bih, bhh, h0i, h0o, nullptr};
  };
  // encoder layer-1, step u: activation = h0 slot((u+1)&1), state = h1 slot(u&1)
  auto mkL1e = [&](int u) {
    const u16* act = pl_h0 + (size_t)((u + 1) & 1) * 262144;
    const u16* h1i = pl_h1 + (size_t)(u & 1) * 262144;
    u16* h1o = pl_h1 + (size_t)((u + 1) & 1) * 262144;
    return GArgs{act, pl_eWih1, 16, h1i, pl_eWhh1, 16, ebih1, ebhh1, h1i, h1o, nullptr};
  };

  // ---------------- encoder: L0[t] || L1[t-1] fused ----------------
  {
    GArgs g0 = mkL0(0, pl_x, ebih0, ebhh0, pl_eWih0, pl_eWhh0);
    fused_gemm<3, 0><<<64, 256, 0, stream>>>(g0);
  }
  for (int t = 1; t < Tdim; ++t) {
    GArgs gA = mkL0(t, pl_x + (size_t)t * 16384, ebih0, ebhh0, pl_eWih0, pl_eWhh0);
    GArgs gB = mkL1e(t - 1);
    gru_pair<<<128, 256, 0, stream>>>(gA, gB);
  }
  {
    GArgs gB = mkL1e(Tdim - 1);
    fused_gemm<3, 0><<<64, 256, 0, stream>>>(gB);
  }

  // ---------------- decoder (serial chain) ----------------
  for (int s = 0; s < OUTLEN; ++s) {
    const u16* xs = (s == 0) ? (pl_x + 255ULL * 16384) : (pl_y + (size_t)((s - 1) & 1) * 16384);
    const u16* h0i = pl_h0 + (size_t)(s & 1) * 262144;
    u16* h0o = pl_h0 + (size_t)((s + 1) & 1) * 262144;
    const u16* h1i = pl_h1 + (size_t)(s & 1) * 262144;
    u16* h1o = pl_h1 + (size_t)((s + 1) & 1) * 262144;

    GArgs g0{xs, pl_dWih0, 1, h0i, pl_dWhh0, 16, dbih0, dbhh0, h0i, h0o, nullptr};
    fused_gemm<3, 0><<<64, 256, 0, stream>>>(g0);
    GArgs g1{h0o, pl_dWih1, 16, h1i, pl_dWhh1, 16, dbih1, dbhh1, h1i, h1o, nullptr};
    fused_gemm<3, 0><<<64, 256, 0, stream>>>(g1);
    GArgs gp{h1o, pl_proj, 16, nullptr, nullptr, 0, projb, nullptr, nullptr, pl_p, nullptr};
    fused_gemm<1, 1><<<32, 256, 0, stream>>>(gp);
    GArgs gy{pl_p, pl_out, 8, nullptr, nullptr, 0, outb, nullptr, nullptr,
             pl_y + (size_t)(s & 1) * 16384, outf + (size_t)s * 64};
    fused_gemm<1, 2><<<4, 256, 0, stream>>>(gy);
  }
}

// Round 9
// 11924.205 us; speedup vs baseline: 5.9875x; 1.1097x over previous
//
#include <hip/hip_runtime.h>

#define Bdim 128
#define Tdim 256
#define Fdim 64
#define Hdim 1024
#define Pdim 512
#define OUTLEN 48

typedef float  f32x4 __attribute__((ext_vector_type(4)));
typedef short  s16x8 __attribute__((ext_vector_type(8)));
typedef unsigned short u16;

__device__ __forceinline__ u16 f2bf(float f) {
  unsigned u = __float_as_uint(f);
  u += 0x7FFFu + ((u >> 16) & 1u);   // RNE
  return (u16)(u >> 16);
}
__device__ __forceinline__ float bf2f(u16 s) { return __uint_as_float(((unsigned)s) << 16); }
// 16B-block XOR swizzle within a 128B row (G4 pattern); returns u16 offset of block
__device__ __forceinline__ int swz8(int row, int blk) { return ((blk ^ (row & 7)) << 3); }

__device__ __forceinline__ f32x4 mfma16(s16x8 a, s16x8 b, f32x4 c) {
  return __builtin_amdgcn_mfma_f32_16x16x32_bf16(a, b, c, 0, 0, 0);
}

// async global->LDS, 16B per lane; lds base must be wave-uniform (HW adds lane*16)
__device__ __forceinline__ void glds16(u16* lds, const u16* g) {
  __builtin_amdgcn_global_load_lds(
      (const __attribute__((address_space(1))) unsigned int*)g,
      (__attribute__((address_space(3))) unsigned int*)lds, 16, 0, 0);
}

// =====================================================================
// prep: fp32 weight [N][K] -> swizzled bf16 hi/lo plane tiles
// layout: [colblk][nc][2(hi,lo)][rows][64]  (rows = 48 gru / 16 lin)
// =====================================================================
__global__ __launch_bounds__(256)
void prep_w(const float* __restrict__ W, u16* __restrict__ dst,
            int colblks, int nc, int rows, int K, int gru) {
  int idx = blockIdx.x * 256 + threadIdx.x;
  if (idx >= colblks * nc * rows * 8) return;
  int blk = idx & 7;
  int t = idx >> 3;
  int r = t % rows; t /= rows;
  int c = t % nc;
  int cb = t / nc;
  int srow = gru ? ((r >> 4) * Hdim + cb * 16 + (r & 15)) : (cb * 16 + r);
  const float* src = W + (size_t)srow * K + c * 64 + blk * 8;
  s16x8 vh, vl;
#pragma unroll
  for (int e = 0; e < 8; ++e) {
    float v = src[e];
    u16 h = f2bf(v);
    vh[e] = (short)h;
    vl[e] = (short)f2bf(v - bf2f(h));
  }
  size_t tb = (size_t)(cb * nc + c) * (2 * rows * 64);
  int o = r * 64 + swz8(r, blk);
  *(s16x8*)(dst + tb + o) = vh;
  *(s16x8*)(dst + tb + (size_t)rows * 64 + o) = vl;
}

// X [128][256][64] fp32 -> per-t A-tiles [256][2][128][64]
__global__ __launch_bounds__(256)
void prep_x(const float* __restrict__ X, u16* __restrict__ dst) {
  int idx = blockIdx.x * 256 + threadIdx.x;   // 256*128*8
  int blk = idx & 7;
  int row = (idx >> 3) & 127;
  int t = idx >> 10;
  const float* src = X + (size_t)row * (Tdim * Fdim) + t * 64 + blk * 8;
  s16x8 vh, vl;
#pragma unroll
  for (int e = 0; e < 8; ++e) {
    float v = src[e];
    u16 h = f2bf(v);
    vh[e] = (short)h;
    vl[e] = (short)f2bf(v - bf2f(h));
  }
  size_t tb = (size_t)t * 16384;
  int o = row * 64 + swz8(row, blk);
  *(s16x8*)(dst + tb + o) = vh;
  *(s16x8*)(dst + tb + 8192 + o) = vl;
}

// =====================================================================
// one staged 64-k chunk (3-term hi/lo split), M-split form (64 rows/block):
// LDS buf: A hi[64][64] (4096 u16) | A lo (4096) | W hi[NG*16][64] | W lo
// each of 4 waves owns 16 A-rows -> one MFMA row-tile (no mf loop)
// =====================================================================
template<int NG, bool SEG1>
__device__ __forceinline__ void compute_chunk(const u16* __restrict__ A, int lane, int wv,
                                              f32x4* acc) {
  constexpr int WT = NG * 1024;
  const u16* Wp = A + 8192;
#pragma unroll
  for (int kk = 0; kk < 2; ++kk) {
    const int sw = (((kk * 4 + (lane >> 4)) ^ (lane & 7)) << 3);
    s16x8 bh[NG], bl[NG];
#pragma unroll
    for (int g = 0; g < NG; ++g) {
      const u16* wp = Wp + (g * 16 + (lane & 15)) * 64 + sw;
      bh[g] = *(const s16x8*)(wp);
      bl[g] = *(const s16x8*)(wp + WT);
    }
    const u16* ap = A + (wv * 16 + (lane & 15)) * 64 + sw;
    s16x8 ah = *(const s16x8*)(ap);
    s16x8 al = *(const s16x8*)(ap + 4096);
#pragma unroll
    for (int g = 0; g < NG; ++g) {
      const int q = (NG == 3 && g == 2) ? (SEG1 ? 3 : 2) : g;
      acc[q] = mfma16(ah, bh[g], acc[q]);
      acc[q] = mfma16(al, bh[g], acc[q]);
      acc[q] = mfma16(ah, bl[g], acc[q]);
    }
  }
}

// =====================================================================
// argument bundle for one GEMM instance (so two can share a launch)
// =====================================================================
struct GArgs {
  const u16* a0; const u16* w0; int nc0;
  const u16* a1; const u16* w1; int nc1;
  const float* bias0; const float* bias1;
  const u16* hprev; u16* oplanes; float* yout;
};

// =====================================================================
// GEMM body: full-K per block, M-split (rh = row-half), 5 LDS buffers,
// prefetch depth 4, direct register epilogue. No inter-block comms.
// NG=3 MODE=0: GRU (R,Z,IN,HN; epilogue -> h planes)
// NG=1 MODE=1: proj+relu -> p planes; MODE=2: out -> y planes + f32 d_out
// =====================================================================
template<int NG, int MODE>
__device__ __forceinline__ void gemm_body(u16* __restrict__ sm, const GArgs& g,
                                          int cb, int rh) {
  constexpr int WT = NG * 1024;            // u16 per W plane tile
  constexpr int BUFU = 8192 + 2 * WT;      // A(hi+lo, 64 rows) + W(hi+lo)
  constexpr int NQ = (NG == 3) ? 4 : 1;
  constexpr int D = 4;                     // prefetch depth (5 buffers)

  const int tid = threadIdx.x;
  const int lane = tid & 63;
  const int wv = tid >> 6;
  const int nc0 = g.nc0;
  const int NC = nc0 + g.nc1;

  f32x4 acc[NQ];
#pragma unroll
  for (int q = 0; q < NQ; ++q) acc[q] = f32x4{0.f, 0.f, 0.f, 0.f};

  auto stage = [&](int c, int buf) {
    const u16 *at, *wt;
    if (c < nc0) { at = g.a0 + (size_t)c * 16384; wt = g.w0 + (size_t)(cb * nc0 + c) * (2 * WT); }
    else { int cc = c - nc0; at = g.a1 + (size_t)cc * 16384; wt = g.w1 + (size_t)(cb * g.nc1 + cc) * (2 * WT); }
    u16* sa = sm + buf * BUFU;
    for (int i = wv; i < 16; i += 4)                 // A half: 16 KB -> 4 issues/wave
      glds16(sa + i * 512, at + ((i & 8) ? 8192 : 0) + rh * 4096 + (i & 7) * 512 + lane * 8);
    u16* swl = sa + 8192;
    for (int i = wv; i < (WT >> 8); i += 4)          // W: GRU 3/wave, LIN 1/wave
      glds16(swl + i * 512, wt + i * 512 + lane * 8);
  };
  // per-wave issues per stage: 4 + (WT>>8)/4 -> 7 (GRU) / 5 (linear)

  for (int p = 0; p < D && p < NC; ++p) stage(p, p % 5);
  for (int c = 0; c < NC; ++c) {
    if (c + D < NC) stage(c + D, (c + D) % 5);
    const int rem = NC - 1 - c;
    const int gg = rem < D ? rem : D;                // stage-groups newer than c
    if constexpr (NG == 3) {
      switch (gg) {
        case 4:  asm volatile("s_waitcnt vmcnt(28)" ::: "memory"); break;
        case 3:  asm volatile("s_waitcnt vmcnt(21)" ::: "memory"); break;
        case 2:  asm volatile("s_waitcnt vmcnt(14)" ::: "memory"); break;
        case 1:  asm volatile("s_waitcnt vmcnt(7)"  ::: "memory"); break;
        default: asm volatile("s_waitcnt vmcnt(0)"  ::: "memory");
      }
    } else {
      switch (gg) {
        case 4:  asm volatile("s_waitcnt vmcnt(20)" ::: "memory"); break;
        case 3:  asm volatile("s_waitcnt vmcnt(15)" ::: "memory"); break;
        case 2:  asm volatile("s_waitcnt vmcnt(10)" ::: "memory"); break;
        case 1:  asm volatile("s_waitcnt vmcnt(5)"  ::: "memory"); break;
        default: asm volatile("s_waitcnt vmcnt(0)"  ::: "memory");
      }
    }
    __builtin_amdgcn_s_barrier();
    asm volatile("" ::: "memory");
    const u16* A = sm + (c % 5) * BUFU;
    if (c < nc0) compute_chunk<NG, false>(A, lane, wv, acc);
    else         compute_chunk<NG, true>(A, lane, wv, acc);
    asm volatile("s_waitcnt lgkmcnt(0)" ::: "memory");
    __builtin_amdgcn_s_barrier();
    asm volatile("" ::: "memory");
  }

  // ---- epilogue (C layout: col=lane&15, row(local)=wv*16+(lane>>4)*4+e) ----
  const int j = cb * 16 + (lane & 15);
  const int ch = j >> 6, k6 = j & 63;
  const int rowbase = rh * 64 + wv * 16 + ((lane >> 4) << 2);

  if constexpr (MODE == 0) {
    const float b_r = g.bias0[j] + g.bias1[j];
    const float b_z = g.bias0[Hdim + j] + g.bias1[Hdim + j];
    const float b_in = g.bias0[2 * Hdim + j];
    const float b_hn = g.bias1[2 * Hdim + j];
#pragma unroll
    for (int e = 0; e < 4; ++e) {
      const int r = rowbase + e;
      const int o = ch * 16384 + r * 64 + swz8(r, k6 >> 3) + (k6 & 7);
      const float hp = bf2f(g.hprev[o]) + bf2f(g.hprev[o + 8192]);
      const float rr = 1.f / (1.f + expf(-(acc[0][e] + b_r)));
      const float zz = 1.f / (1.f + expf(-(acc[1][e] + b_z)));
      const float nn = tanhf(acc[2][e] + b_in + rr * (acc[3][e] + b_hn));
      const float h = (1.f - zz) * nn + zz * hp;
      const u16 hh = f2bf(h);
      g.oplanes[o] = hh;
      g.oplanes[o + 8192] = f2bf(h - bf2f(hh));
    }
  } else {
    const float bb = g.bias0[j];
#pragma unroll
    for (int e = 0; e < 4; ++e) {
      const int r = rowbase + e;
      float v = acc[0][e] + bb;
      if constexpr (MODE == 1) v = fmaxf(v, 0.f);
      const int o = ch * 16384 + r * 64 + swz8(r, k6 >> 3) + (k6 & 7);
      const u16 hh = f2bf(v);
      g.oplanes[o] = hh;
      g.oplanes[o + 8192] = f2bf(v - bf2f(hh));
      if constexpr (MODE == 2) g.yout[(size_t)r * (OUTLEN * Fdim) + j] = v;
    }
  }
}

template<int NG, int MODE>
__global__ __launch_bounds__(256)
void fused_gemm(GArgs g) {
  __shared__ u16 sm[5 * (8192 + 2 * NG * 1024)];
  gemm_body<NG, MODE>(sm, g, blockIdx.x, blockIdx.y);
}

// encoder pair: x<64 -> layer-0 step t, x>=64 -> layer-1 step t-1; y = row-half
__global__ __launch_bounds__(256)
void gru_pair(GArgs ga, GArgs gb) {
  __shared__ u16 sm[5 * (8192 + 2 * 3 * 1024)];
  if (blockIdx.x < 64) gemm_body<3, 0>(sm, ga, blockIdx.x, blockIdx.y);
  else                 gemm_body<3, 0>(sm, gb, blockIdx.x - 64, blockIdx.y);
}

// =====================================================================
extern "C" void kernel_launch(void* const* d_in, const int* in_sizes, int n_in,
                              void* d_out, int out_size, void* d_ws, size_t ws_size,
                              hipStream_t stream) {
  const float* X     = (const float*)d_in[0];
  const float* eWih0 = (const float*)d_in[1];
  const float* eWhh0 = (const float*)d_in[2];
  const float* ebih0 = (const float*)d_in[3];
  const float* ebhh0 = (const float*)d_in[4];
  const float* eWih1 = (const float*)d_in[5];
  const float* eWhh1 = (const float*)d_in[6];
  const float* ebih1 = (const float*)d_in[7];
  const float* ebhh1 = (const float*)d_in[8];
  const float* dWih0 = (const float*)d_in[9];
  const float* dWhh0 = (const float*)d_in[10];
  const float* dbih0 = (const float*)d_in[11];
  const float* dbhh0 = (const float*)d_in[12];
  const float* dWih1 = (const float*)d_in[13];
  const float* dWhh1 = (const float*)d_in[14];
  const float* dbih1 = (const float*)d_in[15];
  const float* dbhh1 = (const float*)d_in[16];
  const float* projW = (const float*)d_in[17];
  const float* projb = (const float*)d_in[18];
  const float* outW  = (const float*)d_in[19];
  const float* outb  = (const float*)d_in[20];
  float* outf = (float*)d_out;

  u16* wsp = (u16*)d_ws;
  size_t off = 0;
  auto take = [&](size_t n) { u16* p = wsp + off; off += n; return p; };

  u16* pl_eWih0 = take(64ULL * 1 * 2 * 48 * 64);
  u16* pl_eWhh0 = take(64ULL * 16 * 2 * 48 * 64);
  u16* pl_eWih1 = take(64ULL * 16 * 2 * 48 * 64);
  u16* pl_eWhh1 = take(64ULL * 16 * 2 * 48 * 64);
  u16* pl_dWih0 = take(64ULL * 1 * 2 * 48 * 64);
  u16* pl_dWhh0 = take(64ULL * 16 * 2 * 48 * 64);
  u16* pl_dWih1 = take(64ULL * 16 * 2 * 48 * 64);
  u16* pl_dWhh1 = take(64ULL * 16 * 2 * 48 * 64);
  u16* pl_proj  = take(32ULL * 16 * 2 * 16 * 64);
  u16* pl_out   = take(4ULL * 8 * 2 * 16 * 64);
  u16* pl_x     = take(256ULL * 2 * 128 * 64);
  u16* pl_h0    = take(2ULL * 16 * 2 * 128 * 64);   // 2 slots, stride 262144
  u16* pl_h1    = take(2ULL * 16 * 2 * 128 * 64);
  u16* pl_y     = take(2ULL * 1 * 2 * 128 * 64);    // 2 slots, stride 16384
  u16* pl_p     = take(8ULL * 2 * 128 * 64);
  if (off * 2 > ws_size) return;                    // scratch too small -> loud fail

  hipMemsetAsync(pl_h0, 0, 262144 * 2, stream);     // h0 slot0 = 0
  hipMemsetAsync(pl_h1, 0, 262144 * 2, stream);     // h1 slot0 = 0

  auto pw = [&](const float* W, u16* dst, int colblks, int nc, int rows, int K, int gru) {
    int total = colblks * nc * rows * 8;
    prep_w<<<(total + 255) / 256, 256, 0, stream>>>(W, dst, colblks, nc, rows, K, gru);
  };
  pw(eWih0, pl_eWih0, 64, 1, 48, 64, 1);
  pw(eWhh0, pl_eWhh0, 64, 16, 48, 1024, 1);
  pw(eWih1, pl_eWih1, 64, 16, 48, 1024, 1);
  pw(eWhh1, pl_eWhh1, 64, 16, 48, 1024, 1);
  pw(dWih0, pl_dWih0, 64, 1, 48, 64, 1);
  pw(dWhh0, pl_dWhh0, 64, 16, 48, 1024, 1);
  pw(dWih1, pl_dWih1, 64, 16, 48, 1024, 1);
  pw(dWhh1, pl_dWhh1, 64, 16, 48, 1024, 1);
  pw(projW, pl_proj, 32, 16, 16, 1024, 0);
  pw(outW,  pl_out,  4,  8,  16, 512, 0);
  prep_x<<<1024, 256, 0, stream>>>(X, pl_x);

  // nc0 MUST be threaded through: 1 for x-input (K=64), 16 for h-input (K=1024).
  auto mkL0 = [&](int t, const u16* xs, const float* bih, const float* bhh,
                  const u16* wih, const u16* whh) {
    const u16* h0i = pl_h0 + (size_t)(t & 1) * 262144;
    u16* h0o = pl_h0 + (size_t)((t + 1) & 1) * 262144;
    return GArgs{xs, wih, 1, h0i, whh, 16, bih, bhh, h0i, h0o, nullptr};
  };
  // encoder layer-1, step u: activation = h0 slot((u+1)&1), state = h1 slot(u&1)
  auto mkL1e = [&](int u) {
    const u16* act = pl_h0 + (size_t)((u + 1) & 1) * 262144;
    const u16* h1i = pl_h1 + (size_t)(u & 1) * 262144;
    u16* h1o = pl_h1 + (size_t)((u + 1) & 1) * 262144;
    return GArgs{act, pl_eWih1, 16, h1i, pl_eWhh1, 16, ebih1, ebhh1, h1i, h1o, nullptr};
  };

  // ---------------- encoder: L0[t] || L1[t-1] fused ----------------
  {
    GArgs g0 = mkL0(0, pl_x, ebih0, ebhh0, pl_eWih0, pl_eWhh0);
    fused_gemm<3, 0><<<dim3(64, 2), 256, 0, stream>>>(g0);
  }
  for (int t = 1; t < Tdim; ++t) {
    GArgs gA = mkL0(t, pl_x + (size_t)t * 16384, ebih0, ebhh0, pl_eWih0, pl_eWhh0);
    GArgs gB = mkL1e(t - 1);
    gru_pair<<<dim3(128, 2), 256, 0, stream>>>(gA, gB);
  }
  {
    GArgs gB = mkL1e(Tdim - 1);
    fused_gemm<3, 0><<<dim3(64, 2), 256, 0, stream>>>(gB);
  }

  // ---------------- decoder (serial chain) ----------------
  for (int s = 0; s < OUTLEN; ++s) {
    const u16* xs = (s == 0) ? (pl_x + 255ULL * 16384) : (pl_y + (size_t)((s - 1) & 1) * 16384);
    const u16* h0i = pl_h0 + (size_t)(s & 1) * 262144;
    u16* h0o = pl_h0 + (size_t)((s + 1) & 1) * 262144;
    const u16* h1i = pl_h1 + (size_t)(s & 1) * 262144;
    u16* h1o = pl_h1 + (size_t)((s + 1) & 1) * 262144;

    GArgs g0{xs, pl_dWih0, 1, h0i, pl_dWhh0, 16, dbih0, dbhh0, h0i, h0o, nullptr};
    fused_gemm<3, 0><<<dim3(64, 2), 256, 0, stream>>>(g0);
    GArgs g1{h0o, pl_dWih1, 16, h1i, pl_dWhh1, 16, dbih1, dbhh1, h1i, h1o, nullptr};
    fused_gemm<3, 0><<<dim3(64, 2), 256, 0, stream>>>(g1);
    GArgs gp{h1o, pl_proj, 16, nullptr, nullptr, 0, projb, nullptr, nullptr, pl_p, nullptr};
    fused_gemm<1, 1><<<dim3(32, 2), 256, 0, stream>>>(gp);
    GArgs gy{pl_p, pl_out, 8, nullptr, nullptr, 0, outb, nullptr, nullptr,
             pl_y + (size_t)(s & 1) * 16384, outf + (size_t)s * 64};
    fused_gemm<1, 2><<<dim3(4, 2), 256, 0, stream>>>(gy);
  }
}